// Round 3
// baseline (433.639 us; speedup 1.0000x reference)
//
#include <hip/hip_runtime.h>

#define T_TOK 2048
#define H_DIM 1024
#define E_NUM 16
#define F_DIM 1024

typedef unsigned short u16;
typedef unsigned int u32;
typedef short s16x8 __attribute__((ext_vector_type(8)));
typedef float f32x4 __attribute__((ext_vector_type(4)));

__device__ __forceinline__ float b2f(u16 v) { return __uint_as_float(((u32)v) << 16); }
__device__ __forceinline__ u16 f2b(float f) {
  u32 u = __float_as_uint(f);
  return (u16)((u + 0x7fffu + ((u >> 16) & 1u)) >> 16);
}

// ---------------- router (fp32): logits, top-2, softmax, counts ----------------
__global__ void router_kernel(const float* __restrict__ hidden, const float* __restrict__ rw,
                              int* __restrict__ counts, int* __restrict__ routing_e,
                              float* __restrict__ routing_w) {
  int t = blockIdx.x;
  int lane = threadIdx.x;  // 64
  const float* xrow = hidden + (size_t)t * H_DIM;
  float acc[E_NUM];
#pragma unroll
  for (int e = 0; e < E_NUM; ++e) acc[e] = 0.f;
  for (int j = 0; j < H_DIM / 64; ++j) {
    int h = j * 64 + lane;
    float x = xrow[h];
    const float* wr = rw + h * E_NUM;
#pragma unroll
    for (int e = 0; e < E_NUM; ++e) acc[e] += x * wr[e];
  }
#pragma unroll
  for (int e = 0; e < E_NUM; ++e) {
    acc[e] += __shfl_xor(acc[e], 32, 64);
    acc[e] += __shfl_xor(acc[e], 16, 64);
    acc[e] += __shfl_xor(acc[e], 8, 64);
    acc[e] += __shfl_xor(acc[e], 4, 64);
    acc[e] += __shfl_xor(acc[e], 2, 64);
    acc[e] += __shfl_xor(acc[e], 1, 64);
  }
  if (lane == 0) {
    float v0 = -1e30f, v1 = -1e30f;
    int i0 = 0, i1 = 0;
#pragma unroll
    for (int e = 0; e < E_NUM; ++e) {
      float v = acc[e];
      if (v > v0) { v1 = v0; i1 = i0; v0 = v; i0 = e; }
      else if (v > v1) { v1 = v; i1 = e; }
    }
    float p0 = 1.f / (1.f + __expf(v1 - v0));  // stable: v1 <= v0
    routing_e[2 * t] = i0;
    routing_e[2 * t + 1] = i1;
    routing_w[2 * t] = p0;
    routing_w[2 * t + 1] = 1.f - p0;
    atomicAdd(&counts[i0], 1);
    atomicAdd(&counts[i1], 1);
  }
}

// ---------------- scatter: prefix offsets + slot maps + per-slot weight ----------------
__global__ void scatter_kernel(const int* __restrict__ counts, int* __restrict__ offsets,
                               const int* __restrict__ routing_e, const float* __restrict__ routing_w,
                               int* __restrict__ token_of_slot, float* __restrict__ slot_w) {
  __shared__ int offs[E_NUM];
  __shared__ int cur[E_NUM];
  int tid = threadIdx.x;
  if (tid == 0) {
    int s = 0;
    for (int e = 0; e < E_NUM; ++e) { offs[e] = s; s += counts[e]; }
  }
  __syncthreads();
  if (tid < E_NUM) { offsets[tid] = offs[tid]; cur[tid] = offs[tid]; }
  __syncthreads();
  for (int i = tid; i < 2 * T_TOK; i += 256) {
    int e = routing_e[i];
    int pos = atomicAdd(&cur[e], 1);
    token_of_slot[pos] = i >> 1;
    slot_w[pos] = routing_w[i];
  }
}

// ---- staging helpers: fp32 W k-pair -> LDS [n][k] u32 (k-even|k-odd<<16), XOR swizzle ----
struct f8v { float4 a, b; };

__device__ __forceinline__ void stage_w_pair(u32* __restrict__ B, int kp, int n0,
                                             const f8v& ev, const f8v& od) {
  const float* pe = (const float*)&ev;
  const float* po = (const float*)&od;
  int g0 = kp >> 2, w = kp & 3;
#pragma unroll
  for (int i = 0; i < 8; ++i) {
    int n = n0 + i;
    u32 word = (u32)f2b(pe[i]) | ((u32)f2b(po[i]) << 16);
    B[n * 16 + (((g0 ^ (n >> 3) ^ n) & 3) << 2) + w] = word;
  }
}

__device__ __forceinline__ s16x8 read_bfrag(const u32* __restrict__ B, int n, int q) {
  return *(const s16x8*)&B[n * 16 + (((q ^ (n >> 3) ^ n) & 3) << 2)];
}

// split 8 fp32 -> bf16 hi + bf16 lo(residual), packed for b128 LDS store
__device__ __forceinline__ void split_pack(const float* __restrict__ p, uint4& hh, uint4& ll) {
  u16 h[8], l[8];
#pragma unroll
  for (int i = 0; i < 8; ++i) {
    h[i] = f2b(p[i]);
    l[i] = f2b(p[i] - b2f(h[i]));
  }
  hh.x = (u32)h[0] | ((u32)h[1] << 16);
  hh.y = (u32)h[2] | ((u32)h[3] << 16);
  hh.z = (u32)h[4] | ((u32)h[5] << 16);
  hh.w = (u32)h[6] | ((u32)h[7] << 16);
  ll.x = (u32)l[0] | ((u32)l[1] << 16);
  ll.y = (u32)l[2] | ((u32)l[3] << 16);
  ll.z = (u32)l[4] | ((u32)l[5] << 16);
  ll.w = (u32)l[6] | ((u32)l[7] << 16);
}

#define MFMA(a, b, c) __builtin_amdgcn_mfma_f32_16x16x32_bf16(a, b, c, 0, 0, 0)

// ---------------- GEMM1: act[slot, f] = silu(X@Wg) * (X@Wu)  (fp32 in/out) ----------------
__global__ __launch_bounds__(256, 2) void moe_gemm1(
    const float* __restrict__ hidden, const float* __restrict__ wgu,
    const int* __restrict__ token_of_slot, const int* __restrict__ counts,
    const int* __restrict__ offsets, float* __restrict__ act) {
  const int e = blockIdx.z;
  const int cnt = counts[e];
  const int m0 = blockIdx.y * 64;
  if (m0 >= cnt) return;
  const int off = offsets[e];
  const int f0 = blockIdx.x * 128;

  __shared__ u16 Xh[64][40];
  __shared__ u16 Xl[64][40];
  __shared__ u32 Bg[128 * 16];
  __shared__ u32 Bu[128 * 16];

  const int tid = threadIdx.x;
  const int lane = tid & 63;
  const int wave = tid >> 6;
  const int q = lane >> 4, ln = lane & 15;
  const int mb = (wave & 1) * 32, nb = (wave >> 1) * 64;

  const int xr = tid >> 2, xc = (tid & 3) * 8;
  const int tok = (m0 + xr < cnt) ? token_of_slot[off + m0 + xr] : 0;
  const float* xsrc = hidden + (size_t)tok * H_DIM + xc;

  const int kp = tid >> 4, n0 = (tid & 15) * 8;
  const float* wbase = wgu + (size_t)e * H_DIM * 2048;
  const float* wg0 = wbase + (size_t)(2 * kp) * 2048 + f0 + n0;
  const float* wu0 = wg0 + 1024;

  f32x4 zero = {0.f, 0.f, 0.f, 0.f};
  f32x4 accg[2][4], accu[2][4];
#pragma unroll
  for (int i = 0; i < 2; ++i)
#pragma unroll
    for (int j = 0; j < 4; ++j) { accg[i][j] = zero; accu[i][j] = zero; }

  for (int k0 = 0; k0 < H_DIM; k0 += 32) {
    float4 xa = *(const float4*)(xsrc + k0);
    float4 xb = *(const float4*)(xsrc + k0 + 4);
    size_t wofs = (size_t)k0 * 2048;
    f8v ge, go, ue, uo;
    ge.a = *(const float4*)(wg0 + wofs);
    ge.b = *(const float4*)(wg0 + wofs + 4);
    go.a = *(const float4*)(wg0 + wofs + 2048);
    go.b = *(const float4*)(wg0 + wofs + 2052);
    ue.a = *(const float4*)(wu0 + wofs);
    ue.b = *(const float4*)(wu0 + wofs + 4);
    uo.a = *(const float4*)(wu0 + wofs + 2048);
    uo.b = *(const float4*)(wu0 + wofs + 2052);
    __syncthreads();
    float xv[8] = {xa.x, xa.y, xa.z, xa.w, xb.x, xb.y, xb.z, xb.w};
    uint4 hh, ll;
    split_pack(xv, hh, ll);
    *(uint4*)&Xh[xr][xc] = hh;
    *(uint4*)&Xl[xr][xc] = ll;
    stage_w_pair(Bg, kp, n0, ge, go);
    stage_w_pair(Bu, kp, n0, ue, uo);
    __syncthreads();

    s16x8 ah[2], al[2];
    ah[0] = *(const s16x8*)&Xh[mb + ln][q * 8];
    ah[1] = *(const s16x8*)&Xh[mb + 16 + ln][q * 8];
    al[0] = *(const s16x8*)&Xl[mb + ln][q * 8];
    al[1] = *(const s16x8*)&Xl[mb + 16 + ln][q * 8];
#pragma unroll
    for (int j = 0; j < 4; ++j) {
      s16x8 bg = read_bfrag(Bg, nb + j * 16 + ln, q);
      s16x8 bu = read_bfrag(Bu, nb + j * 16 + ln, q);
#pragma unroll
      for (int i = 0; i < 2; ++i) {
        accg[i][j] = MFMA(ah[i], bg, accg[i][j]);
        accg[i][j] = MFMA(al[i], bg, accg[i][j]);
        accu[i][j] = MFMA(ah[i], bu, accu[i][j]);
        accu[i][j] = MFMA(al[i], bu, accu[i][j]);
      }
    }
  }

#pragma unroll
  for (int i = 0; i < 2; ++i) {
#pragma unroll
    for (int r = 0; r < 4; ++r) {
      int row = mb + i * 16 + q * 4 + r;
      if (m0 + row < cnt) {
        float* arow = act + (size_t)(off + m0 + row) * F_DIM + f0 + nb + ln;
#pragma unroll
        for (int j = 0; j < 4; ++j) {
          float g = accg[i][j][r], u = accu[i][j][r];
          arow[j * 16] = g * (1.f / (1.f + __expf(-g))) * u;
        }
      }
    }
  }
}

// ---------------- GEMM2: out[tok,h] += w_slot * (act @ w_down)  (atomic fp32) ----------------
__global__ __launch_bounds__(256, 2) void moe_gemm2(
    const float* __restrict__ act, const float* __restrict__ wd,
    const int* __restrict__ token_of_slot, const float* __restrict__ slot_w,
    const int* __restrict__ counts, const int* __restrict__ offsets,
    float* __restrict__ out) {
  const int e = blockIdx.z;
  const int cnt = counts[e];
  const int m0 = blockIdx.y * 64;
  if (m0 >= cnt) return;
  const int off = offsets[e];
  const int h0 = blockIdx.x * 128;

  __shared__ u16 Ah[64][40];
  __shared__ u16 Al[64][40];
  __shared__ u32 Bd[128 * 16];

  const int tid = threadIdx.x;
  const int lane = tid & 63;
  const int wave = tid >> 6;
  const int q = lane >> 4, ln = lane & 15;
  const int mb = (wave & 1) * 32, nb = (wave >> 1) * 64;

  const int xr = tid >> 2, xc = (tid & 3) * 8;
  const int gs = (m0 + xr < cnt) ? (off + m0 + xr) : 0;
  const float* asrc = act + (size_t)gs * F_DIM + xc;

  const int kp = tid >> 4, n0 = (tid & 15) * 8;
  const float* wd0 = wd + (size_t)e * F_DIM * H_DIM + (size_t)(2 * kp) * H_DIM + h0 + n0;

  f32x4 zero = {0.f, 0.f, 0.f, 0.f};
  f32x4 acc[2][4];
#pragma unroll
  for (int i = 0; i < 2; ++i)
#pragma unroll
    for (int j = 0; j < 4; ++j) acc[i][j] = zero;

  for (int k0 = 0; k0 < F_DIM; k0 += 32) {
    float4 aa = *(const float4*)(asrc + k0);
    float4 ab = *(const float4*)(asrc + k0 + 4);
    size_t wofs = (size_t)k0 * H_DIM;
    f8v de, dd;
    de.a = *(const float4*)(wd0 + wofs);
    de.b = *(const float4*)(wd0 + wofs + 4);
    dd.a = *(const float4*)(wd0 + wofs + 1024);
    dd.b = *(const float4*)(wd0 + wofs + 1028);
    __syncthreads();
    float av[8] = {aa.x, aa.y, aa.z, aa.w, ab.x, ab.y, ab.z, ab.w};
    uint4 hh, ll;
    split_pack(av, hh, ll);
    *(uint4*)&Ah[xr][xc] = hh;
    *(uint4*)&Al[xr][xc] = ll;
    stage_w_pair(Bd, kp, n0, de, dd);
    __syncthreads();
    s16x8 ah[2], al[2];
    ah[0] = *(const s16x8*)&Ah[mb + ln][q * 8];
    ah[1] = *(const s16x8*)&Ah[mb + 16 + ln][q * 8];
    al[0] = *(const s16x8*)&Al[mb + ln][q * 8];
    al[1] = *(const s16x8*)&Al[mb + 16 + ln][q * 8];
#pragma unroll
    for (int j = 0; j < 4; ++j) {
      s16x8 bf = read_bfrag(Bd, nb + j * 16 + ln, q);
#pragma unroll
      for (int i = 0; i < 2; ++i) {
        acc[i][j] = MFMA(ah[i], bf, acc[i][j]);
        acc[i][j] = MFMA(al[i], bf, acc[i][j]);
      }
    }
  }
#pragma unroll
  for (int i = 0; i < 2; ++i) {
#pragma unroll
    for (int r = 0; r < 4; ++r) {
      int row = mb + i * 16 + q * 4 + r;
      if (m0 + row < cnt) {
        int slot = off + m0 + row;
        int tok = token_of_slot[slot];
        float wgt = slot_w[slot];
        float* orow = out + (size_t)tok * H_DIM + h0 + nb + ln;
#pragma unroll
        for (int j = 0; j < 4; ++j) atomicAdd(&orow[j * 16], wgt * acc[i][j][r]);
      }
    }
  }
}

extern "C" void kernel_launch(void* const* d_in, const int* in_sizes, int n_in,
                              void* d_out, int out_size, void* d_ws, size_t ws_size,
                              hipStream_t stream) {
  const float* hidden = (const float*)d_in[0];  // [2048][1024] f32
  const float* rw = (const float*)d_in[1];      // [1024][16]   f32
  const float* wgu = (const float*)d_in[2];     // [16][1024][2048] f32
  const float* wd = (const float*)d_in[3];      // [16][1024][1024] f32
  float* out = (float*)d_out;                   // [2048][1024] f32
  char* ws = (char*)d_ws;

  // workspace layout (~16.13 MB)
  int* counts = (int*)(ws);                  // 64 B
  int* offsets = (int*)(ws + 256);           // 64 B
  int* routing_e = (int*)(ws + 1024);        // 16 KB
  float* routing_w = (float*)(ws + 17408);   // 16 KB
  int* token_of_slot = (int*)(ws + 33792);   // 16 KB
  float* slot_w = (float*)(ws + 50176);      // 16 KB
  float* act = (float*)(ws + 131072);        // 16 MB [4096][1024] f32

  hipMemsetAsync(counts, 0, 64, stream);
  hipMemsetAsync(out, 0, (size_t)out_size * sizeof(float), stream);
  router_kernel<<<dim3(T_TOK), dim3(64), 0, stream>>>(hidden, rw, counts, routing_e, routing_w);
  scatter_kernel<<<dim3(1), dim3(256), 0, stream>>>(counts, offsets, routing_e, routing_w,
                                                    token_of_slot, slot_w);
  moe_gemm1<<<dim3(8, 32, E_NUM), dim3(256), 0, stream>>>(hidden, wgu, token_of_slot, counts,
                                                          offsets, act);
  moe_gemm2<<<dim3(8, 32, E_NUM), dim3(256), 0, stream>>>(act, wd, token_of_slot, slot_w, counts,
                                                          offsets, out);
}